// Round 3
// baseline (828.281 us; speedup 1.0000x reference)
//
#include <hip/hip_runtime.h>
#include <cstdint>
#include <cstddef>

typedef __bf16 bf16;
typedef bf16 bf16x8 __attribute__((ext_vector_type(8)));
typedef float f32x4 __attribute__((ext_vector_type(4)));
typedef unsigned short u16;
typedef u16 u16x4 __attribute__((ext_vector_type(4)));
typedef u16 u16x8 __attribute__((ext_vector_type(8)));

__device__ __forceinline__ u16 f2bf(float f) {
    uint32_t u = __builtin_bit_cast(uint32_t, f);
    u += 0x7FFFu + ((u >> 16) & 1u);
    return (u16)(u >> 16);
}

#define AS1C(p) ((const __attribute__((address_space(1))) uint32_t*)(p))
#define AS3(p)  ((__attribute__((address_space(3))) uint32_t*)(p))
#define MFMA16  __builtin_amdgcn_mfma_f32_16x16x32_bf16

// ---------------------------------------------------------------------------
// OLD core (m97 structure) — kept for gemm_states / gemm_out.
// C[128x128] += A[128xK] * Bt[128xK]^T   (both operands K-contiguous)
// ---------------------------------------------------------------------------
__device__ __forceinline__ void gemm_core(const bf16* __restrict__ Ablk,
                                          const bf16* __restrict__ Btblk,
                                          int lda, int ldb, int K,
                                          f32x4 acc[4][4])
{
    __shared__ bf16 lA[4096];   // [128 rows][32 k] row-major, no pad (gld_lds)
    __shared__ bf16 lB[4096];

    const int tid  = threadIdx.x;
    const int wave = tid >> 6;
    const int lane = tid & 63;
    const int lrow = lane >> 2;          // 0..15
    const int kcol = (lane & 3) << 3;    // 0,8,16,24

    const bf16* ga0 = Ablk  + (size_t)(wave * 32 + lrow) * lda + kcol;
    const bf16* ga1 = ga0 + (size_t)16 * lda;
    const bf16* gb0 = Btblk + (size_t)(wave * 32 + lrow) * ldb + kcol;
    const bf16* gb1 = gb0 + (size_t)16 * ldb;
    bf16* la0 = &lA[wave * 1024];
    bf16* la1 = &lA[wave * 1024 + 512];
    bf16* lb0 = &lB[wave * 1024];
    bf16* lb1 = &lB[wave * 1024 + 512];

    const int wm    = (wave >> 1) * 64;
    const int wn    = (wave & 1) * 64;
    const int col16 = lane & 15;
    const int quad  = lane >> 4;
    const bf16* pa = &lA[(wm + col16) * 32 + quad * 8];
    const bf16* pb = &lB[(wn + col16) * 32 + quad * 8];

    for (int kb = 0; kb < K; kb += 32) {
        __builtin_amdgcn_global_load_lds(AS1C(ga0 + kb), AS3(la0), 16, 0, 0);
        __builtin_amdgcn_global_load_lds(AS1C(ga1 + kb), AS3(la1), 16, 0, 0);
        __builtin_amdgcn_global_load_lds(AS1C(gb0 + kb), AS3(lb0), 16, 0, 0);
        __builtin_amdgcn_global_load_lds(AS1C(gb1 + kb), AS3(lb1), 16, 0, 0);
        __syncthreads();

        bf16x8 av[4], bv[4];
        #pragma unroll
        for (int i = 0; i < 4; ++i) av[i] = *(const bf16x8*)(pa + i * 512);
        #pragma unroll
        for (int i = 0; i < 4; ++i) bv[i] = *(const bf16x8*)(pb + i * 512);

        #pragma unroll
        for (int mi = 0; mi < 4; ++mi)
            #pragma unroll
            for (int ni = 0; ni < 4; ++ni)
                acc[mi][ni] = MFMA16(av[mi], bv[ni], acc[mi][ni], 0, 0, 0);
        __syncthreads();
    }
}

// ---------------------------------------------------------------------------
// fp32 -> bf16 cast, 8 elems/thread
// ---------------------------------------------------------------------------
__global__ __launch_bounds__(256) void cast_bf16(const float* __restrict__ src,
                                                 u16* __restrict__ dst, int n8)
{
    int i = blockIdx.x * 256 + threadIdx.x;
    if (i >= n8) return;
    const float4* s = (const float4*)src + (size_t)i * 2;
    float4 f0 = s[0], f1 = s[1];
    u16x8 o;
    o[0] = f2bf(f0.x); o[1] = f2bf(f0.y); o[2] = f2bf(f0.z); o[3] = f2bf(f0.w);
    o[4] = f2bf(f1.x); o[5] = f2bf(f1.y); o[6] = f2bf(f1.z); o[7] = f2bf(f1.w);
    *((u16x8*)dst + i) = o;
}

// ---------------------------------------------------------------------------
// reduce 2 f32 partials + cast to bf16, 4 elems/thread
// ---------------------------------------------------------------------------
__global__ __launch_bounds__(256) void reduce_cast(const float* __restrict__ sp,
                                                   u16* __restrict__ dst, int n4)
{
    int i = blockIdx.x * 256 + threadIdx.x;
    if (i >= n4) return;
    float4 a = ((const float4*)sp)[i];
    float4 b = ((const float4*)(sp + 4194304))[i];
    u16x4 o;
    o[0] = f2bf(a.x + b.x); o[1] = f2bf(a.y + b.y);
    o[2] = f2bf(a.z + b.z); o[3] = f2bf(a.w + b.w);
    ((u16x4*)dst)[i] = o;
}

// ---------------------------------------------------------------------------
// GEMM1: fused QKV projection — 256x256-tile deep-pipelined core.
//   512 thr (8 waves: 2M x 4N), BK=32, 3-deep LDS ring (96 KB),
//   counted vmcnt(4) (never 0 in main loop), T2 XOR-swizzle,
//   m201 lockstep phase: reads -> GLD -> barrier -> lgkmcnt(0) -> MFMA -> barrier.
// ---------------------------------------------------------------------------
__global__ __launch_bounds__(512, 2) void gemm_qkv(
    const bf16* __restrict__ xb,
    const bf16* __restrict__ Wkb, const bf16* __restrict__ Wqb, const bf16* __restrict__ Wvb,
    const float* __restrict__ bk, const float* __restrict__ bq, const float* __restrict__ bv,
    u16* __restrict__ qout, u16* __restrict__ kT, u16* __restrict__ vT)
{
    __shared__ bf16 smem[49152];          // 96 KB = 3 bufs x (A 16KB + B 16KB)
    char* sm = (char*)smem;

    const int bx = blockIdx.x;            // m block 0..63 (256 rows each)
    const int by = blockIdx.y;            // n block 0..23
    const int region = by >> 3;           // 0:k 1:q 2:v
    const int nloc = (by & 7) << 8;       // n offset within region, 0..1792

    const bf16* W     = (region == 0) ? Wkb : (region == 1) ? Wqb : Wvb;
    const float* bias = (region == 0) ? bk  : (region == 1) ? bq  : bv;

    const bf16* Ablk = xb + (size_t)bx * 256 * 2048;
    const bf16* Bblk = W  + (size_t)nloc * 2048;
    const int lda = 2048, ldb = 2048;
    const int NT = 2048 / 32;             // 64 K-tiles

    const int tid  = threadIdx.x;
    const int wave = tid >> 6;
    const int lane = tid & 63;
    const int col16 = lane & 15;
    const int quad  = lane >> 4;
    const int wm = (wave >> 2) * 128;     // 2 waves in M
    const int wn = (wave & 3) * 64;       // 4 waves in N

    // ---- staging: per-thread pre-swizzled global sources ----
    const int P0 = tid * 16;
    const int T0 = P0 ^ ((P0 >> 2) & 0x70) ^ ((P0 >> 4) & 0x10);
    const int r0 = T0 >> 6;               // 0..127
    const int ce = (T0 & 63) >> 1;        // element col offset, mult of 8
    const bf16* gA0 = Ablk + (size_t)r0 * lda + ce;
    const bf16* gA1 = Ablk + (size_t)(r0 + 128) * lda + ce;
    const bf16* gB0 = Bblk + (size_t)r0 * ldb + ce;
    const bf16* gB1 = Bblk + (size_t)(r0 + 128) * ldb + ce;
    const int dA0 = wave * 1024;          // wave-uniform LDS dest bases
    const int dA1 = 8192  + wave * 1024;
    const int dB0 = 16384 + wave * 1024;
    const int dB1 = 24576 + wave * 1024;

    // ---- swizzled read offsets (constant across tiles) ----
    int offA[8], offB[4];
    #pragma unroll
    for (int mi = 0; mi < 8; ++mi) {
        int T = (wm + mi * 16 + col16) * 64 + quad * 16;
        offA[mi] = T ^ ((T >> 2) & 0x70);
    }
    #pragma unroll
    for (int ni = 0; ni < 4; ++ni) {
        int T = (wn + ni * 16 + col16) * 64 + quad * 16;
        offB[ni] = 16384 + (T ^ ((T >> 2) & 0x70));
    }

    f32x4 acc[8][4] = {};

#define GLD(src, dst) __builtin_amdgcn_global_load_lds(AS1C(src), AS3(sm + (dst)), 16, 0, 0)

    // ---- prologue: stage tile 0 -> buf0, tile 1 -> buf1 ----
    GLD(gA0,      0 + dA0); GLD(gB0,      0 + dB0);
    GLD(gA1,      0 + dA1); GLD(gB1,      0 + dB1);
    GLD(gA0 + 32, 32768 + dA0); GLD(gB0 + 32, 32768 + dB0);
    GLD(gA1 + 32, 32768 + dA1); GLD(gB1 + 32, 32768 + dB1);
    asm volatile("s_waitcnt vmcnt(4)" ::: "memory");   // tile 0 landed
    __builtin_amdgcn_s_barrier();
    asm volatile("" ::: "memory");

    int buf = 0, sb = 2;
    for (int t = 0; t < NT; ++t) {
        const int  bb  = buf * 32768;
        const int  sbb = sb  * 32768;
        const int  kb  = (t + 2) * 32;
        const bool st  = (t + 2) < NT;

        // ================= phase A: mi 0-3 x ni 0-3 =================
        bf16x8 a0 = *(const bf16x8*)(sm + bb + offA[0]);
        bf16x8 a1 = *(const bf16x8*)(sm + bb + offA[1]);
        bf16x8 a2 = *(const bf16x8*)(sm + bb + offA[2]);
        bf16x8 a3 = *(const bf16x8*)(sm + bb + offA[3]);
        bf16x8 b0 = *(const bf16x8*)(sm + bb + offB[0]);
        bf16x8 b1 = *(const bf16x8*)(sm + bb + offB[1]);
        bf16x8 b2 = *(const bf16x8*)(sm + bb + offB[2]);
        bf16x8 b3 = *(const bf16x8*)(sm + bb + offB[3]);
        if (st) { GLD(gA0 + kb, sbb + dA0); GLD(gB0 + kb, sbb + dB0); }
        asm volatile("" ::: "memory");
        __builtin_amdgcn_s_barrier();                       // lockstep barrier #1
        asm volatile("s_waitcnt lgkmcnt(0)" ::: "memory");
        __builtin_amdgcn_sched_barrier(0);
        __builtin_amdgcn_s_setprio(1);
        acc[0][0] = MFMA16(a0, b0, acc[0][0], 0, 0, 0);
        acc[0][1] = MFMA16(a0, b1, acc[0][1], 0, 0, 0);
        acc[0][2] = MFMA16(a0, b2, acc[0][2], 0, 0, 0);
        acc[0][3] = MFMA16(a0, b3, acc[0][3], 0, 0, 0);
        acc[1][0] = MFMA16(a1, b0, acc[1][0], 0, 0, 0);
        acc[1][1] = MFMA16(a1, b1, acc[1][1], 0, 0, 0);
        acc[1][2] = MFMA16(a1, b2, acc[1][2], 0, 0, 0);
        acc[1][3] = MFMA16(a1, b3, acc[1][3], 0, 0, 0);
        acc[2][0] = MFMA16(a2, b0, acc[2][0], 0, 0, 0);
        acc[2][1] = MFMA16(a2, b1, acc[2][1], 0, 0, 0);
        acc[2][2] = MFMA16(a2, b2, acc[2][2], 0, 0, 0);
        acc[2][3] = MFMA16(a2, b3, acc[2][3], 0, 0, 0);
        acc[3][0] = MFMA16(a3, b0, acc[3][0], 0, 0, 0);
        acc[3][1] = MFMA16(a3, b1, acc[3][1], 0, 0, 0);
        acc[3][2] = MFMA16(a3, b2, acc[3][2], 0, 0, 0);
        acc[3][3] = MFMA16(a3, b3, acc[3][3], 0, 0, 0);
        __builtin_amdgcn_s_setprio(0);
        asm volatile("" ::: "memory");
        __builtin_amdgcn_s_barrier();                       // phase-end barrier
        asm volatile("" ::: "memory");

        // ================= phase B: mi 4-7 x ni 0-3 =================
        bf16x8 a4 = *(const bf16x8*)(sm + bb + offA[4]);
        bf16x8 a5 = *(const bf16x8*)(sm + bb + offA[5]);
        bf16x8 a6 = *(const bf16x8*)(sm + bb + offA[6]);
        bf16x8 a7 = *(const bf16x8*)(sm + bb + offA[7]);
        if (st) { GLD(gA1 + kb, sbb + dA1); GLD(gB1 + kb, sbb + dB1); }
        if (st) { asm volatile("s_waitcnt vmcnt(4)" ::: "memory"); }  // tile t+1 landed
        else    { asm volatile("s_waitcnt vmcnt(0)" ::: "memory"); }  // epilogue drain
        asm volatile("" ::: "memory");
        __builtin_amdgcn_s_barrier();                       // lockstep barrier #1
        asm volatile("s_waitcnt lgkmcnt(0)" ::: "memory");
        __builtin_amdgcn_sched_barrier(0);
        __builtin_amdgcn_s_setprio(1);
        acc[4][0] = MFMA16(a4, b0, acc[4][0], 0, 0, 0);
        acc[4][1] = MFMA16(a4, b1, acc[4][1], 0, 0, 0);
        acc[4][2] = MFMA16(a4, b2, acc[4][2], 0, 0, 0);
        acc[4][3] = MFMA16(a4, b3, acc[4][3], 0, 0, 0);
        acc[5][0] = MFMA16(a5, b0, acc[5][0], 0, 0, 0);
        acc[5][1] = MFMA16(a5, b1, acc[5][1], 0, 0, 0);
        acc[5][2] = MFMA16(a5, b2, acc[5][2], 0, 0, 0);
        acc[5][3] = MFMA16(a5, b3, acc[5][3], 0, 0, 0);
        acc[6][0] = MFMA16(a6, b0, acc[6][0], 0, 0, 0);
        acc[6][1] = MFMA16(a6, b1, acc[6][1], 0, 0, 0);
        acc[6][2] = MFMA16(a6, b2, acc[6][2], 0, 0, 0);
        acc[6][3] = MFMA16(a6, b3, acc[6][3], 0, 0, 0);
        acc[7][0] = MFMA16(a7, b0, acc[7][0], 0, 0, 0);
        acc[7][1] = MFMA16(a7, b1, acc[7][1], 0, 0, 0);
        acc[7][2] = MFMA16(a7, b2, acc[7][2], 0, 0, 0);
        acc[7][3] = MFMA16(a7, b3, acc[7][3], 0, 0, 0);
        __builtin_amdgcn_s_setprio(0);
        asm volatile("" ::: "memory");
        __builtin_amdgcn_s_barrier();                       // phase-end barrier
        asm volatile("" ::: "memory");

        buf = (buf == 2) ? 0 : buf + 1;
        sb  = (sb  == 2) ? 0 : sb  + 1;
    }
#undef GLD

    // ---- epilogue ----
    if (region == 1) {
        // q: normal store, feature-contiguous
        #pragma unroll
        for (int mi = 0; mi < 8; ++mi) {
            int row = bx * 256 + wm + mi * 16 + quad * 4;
            #pragma unroll
            for (int ni = 0; ni < 4; ++ni) {
                int col = nloc + wn + ni * 16 + col16;
                float b = bias[col];
                #pragma unroll
                for (int r = 0; r < 4; ++r)
                    qout[(size_t)(row + r) * 2048 + col] = f2bf(acc[mi][ni][r] + b);
            }
        }
    } else {
        // k/v: transposed store [bh][d][s]; 4 consecutive s pack to 8B
        u16* T = (region == 0) ? kT : vT;
        const int b_ = bx >> 4;               // 64 m-blocks / 16 per batch
        const int h_ = nloc >> 9;
        const int bh = b_ * 4 + h_;
        #pragma unroll
        for (int mi = 0; mi < 8; ++mi) {
            int s = ((bx & 15) * 256) + wm + mi * 16 + quad * 4;   // within 4096
            #pragma unroll
            for (int ni = 0; ni < 4; ++ni) {
                int fcol = nloc + wn + ni * 16 + col16;  // feature in region
                int d = fcol & 511;
                float b = bias[fcol];
                u16x4 p;
                #pragma unroll
                for (int r = 0; r < 4; ++r) p[r] = f2bf(acc[mi][ni][r] + b);
                *(u16x4*)&T[((size_t)(bh * 512 + d)) * 4096 + s] = p;
            }
        }
    }
}

// ---------------------------------------------------------------------------
// GEMM2: split-K x2.  SP[kh][bh][e][d] (f32) = sum_{s in half} vT*kT.
// Grid (4,4,32): z = bh*2 + kh.  2 blocks/CU -> 2 waves/SIMD (was 1).
// ---------------------------------------------------------------------------
__global__ __launch_bounds__(256) void gemm_states(
    const u16* __restrict__ vT, const u16* __restrict__ kT, float* __restrict__ SP)
{
    const int z  = blockIdx.z;
    const int bh = z >> 1;
    const int kh = z & 1;
    const int m0 = blockIdx.x * 128;   // e
    const int n0 = blockIdx.y * 128;   // d

    f32x4 acc[4][4] = {};
    const size_t base = (size_t)bh * 2097152;
    const size_t koff = (size_t)kh * 2048;
    gemm_core((const bf16*)vT + base + (size_t)m0 * 4096 + koff,
              (const bf16*)kT + base + (size_t)n0 * 4096 + koff,
              4096, 4096, 2048, acc);

    float* P = SP + (size_t)kh * 4194304 + (size_t)bh * 262144;
    const int lane = threadIdx.x & 63, wave = threadIdx.x >> 6;
    const int wm = (wave >> 1) * 64, wn = (wave & 1) * 64;
    const int col16 = lane & 15, quad = lane >> 4;
    #pragma unroll
    for (int mi = 0; mi < 4; ++mi) {
        int row = m0 + wm + mi * 16 + quad * 4;
        #pragma unroll
        for (int ni = 0; ni < 4; ++ni) {
            int col = n0 + wn + ni * 16 + col16;
            #pragma unroll
            for (int r = 0; r < 4; ++r)
                P[(size_t)(row + r) * 512 + col] = acc[mi][ni][r];
        }
    }
}

// ---------------------------------------------------------------------------
// GEMM3: out[bh][s][e] = sum_d q[b][s][h*512+d] * statesT[bh][e][d].  K=512.
// ---------------------------------------------------------------------------
__global__ __launch_bounds__(256) void gemm_out(
    const u16* __restrict__ qb, const u16* __restrict__ ST, float* __restrict__ out)
{
    const int bh = blockIdx.z;
    const int b_ = bh >> 2, h_ = bh & 3;
    const int m0 = blockIdx.x * 128;   // s
    const int n0 = blockIdx.y * 128;   // e

    f32x4 acc[4][4] = {};
    gemm_core((const bf16*)qb + ((size_t)(b_ * 4096 + m0)) * 2048 + h_ * 512,
              (const bf16*)ST + (size_t)bh * 262144 + (size_t)n0 * 512,
              2048, 512, 512, acc);

    const int lane = threadIdx.x & 63, wave = threadIdx.x >> 6;
    const int wm = (wave >> 1) * 64, wn = (wave & 1) * 64;
    const int col16 = lane & 15, quad = lane >> 4;
    #pragma unroll
    for (int mi = 0; mi < 4; ++mi) {
        int row = m0 + wm + mi * 16 + quad * 4;
        #pragma unroll
        for (int ni = 0; ni < 4; ++ni) {
            int col = n0 + wn + ni * 16 + col16;
            #pragma unroll
            for (int r = 0; r < 4; ++r)
                out[(size_t)bh * 2097152 + (size_t)(row + r) * 512 + col] =
                    acc[mi][ni][r];
        }
    }
}

// ---------------------------------------------------------------------------
extern "C" void kernel_launch(void* const* d_in, const int* in_sizes, int n_in,
                              void* d_out, int out_size, void* d_ws, size_t ws_size,
                              hipStream_t stream)
{
    (void)in_sizes; (void)n_in; (void)out_size; (void)ws_size;
    const float* x  = (const float*)d_in[0];
    const float* Wk = (const float*)d_in[1];
    const float* bk = (const float*)d_in[2];
    const float* Wq = (const float*)d_in[3];
    const float* bq = (const float*)d_in[4];
    const float* Wv = (const float*)d_in[5];
    const float* bv = (const float*)d_in[6];
    float* out = (float*)d_out;

    // workspace layout (u16 elements), total 302 MB
    u16* ws  = (u16*)d_ws;
    u16* xb  = ws;                   // 16384*2048 (dead after gemm_qkv -> reused as SP)
    u16* Wkb = ws  + 33554432;       // 2048*2048
    u16* Wqb = Wkb + 4194304;
    u16* Wvb = Wqb + 4194304;
    u16* qb  = Wvb + 4194304;        // 16384*2048 (normal)
    u16* kT  = qb  + 33554432;       // [16][512][4096]
    u16* vT  = kT  + 33554432;       // [16][512][4096]
    u16* ST  = vT  + 33554432;       // [16][512][512]
    float* SP = (float*)xb;          // [2][16][512][512] f32 partials (33.6MB <= 67MB)

    cast_bf16<<<16384, 256, 0, stream>>>(x,  xb,  4194304);
    cast_bf16<<<2048,  256, 0, stream>>>(Wk, Wkb, 524288);
    cast_bf16<<<2048,  256, 0, stream>>>(Wq, Wqb, 524288);
    cast_bf16<<<2048,  256, 0, stream>>>(Wv, Wvb, 524288);

    gemm_qkv<<<dim3(64, 24), 512, 0, stream>>>(
        (const bf16*)xb, (const bf16*)Wkb, (const bf16*)Wqb, (const bf16*)Wvb,
        bk, bq, bv, qb, kT, vT);

    gemm_states<<<dim3(4, 4, 32), 256, 0, stream>>>(vT, kT, SP);
    reduce_cast<<<4096, 256, 0, stream>>>(SP, ST, 1048576);

    gemm_out<<<dim3(32, 4, 16), 256, 0, stream>>>(qb, ST, out);
}

// Round 4
// 794.018 us; speedup vs baseline: 1.0432x; 1.0432x over previous
//
#include <hip/hip_runtime.h>
#include <cstdint>
#include <cstddef>

typedef __bf16 bf16;
typedef bf16 bf16x8 __attribute__((ext_vector_type(8)));
typedef float f32x4 __attribute__((ext_vector_type(4)));
typedef unsigned short u16;
typedef u16 u16x4 __attribute__((ext_vector_type(4)));
typedef u16 u16x8 __attribute__((ext_vector_type(8)));

__device__ __forceinline__ u16 f2bf(float f) {
    uint32_t u = __builtin_bit_cast(uint32_t, f);
    u += 0x7FFFu + ((u >> 16) & 1u);
    return (u16)(u >> 16);
}

#define AS1C(p) ((const __attribute__((address_space(1))) uint32_t*)(p))
#define AS3(p)  ((__attribute__((address_space(3))) uint32_t*)(p))
#define MFMA16  __builtin_amdgcn_mfma_f32_16x16x32_bf16

// ---------------------------------------------------------------------------
// 128x128 m97-structure core — kept for gemm_states.
// C[128x128] += A[128xK] * Bt[128xK]^T   (both operands K-contiguous)
// ---------------------------------------------------------------------------
__device__ __forceinline__ void gemm_core(const bf16* __restrict__ Ablk,
                                          const bf16* __restrict__ Btblk,
                                          int lda, int ldb, int K,
                                          f32x4 acc[4][4])
{
    __shared__ bf16 lA[4096];   // [128 rows][32 k] row-major, no pad (gld_lds)
    __shared__ bf16 lB[4096];

    const int tid  = threadIdx.x;
    const int wave = tid >> 6;
    const int lane = tid & 63;
    const int lrow = lane >> 2;          // 0..15
    const int kcol = (lane & 3) << 3;    // 0,8,16,24

    const bf16* ga0 = Ablk  + (size_t)(wave * 32 + lrow) * lda + kcol;
    const bf16* ga1 = ga0 + (size_t)16 * lda;
    const bf16* gb0 = Btblk + (size_t)(wave * 32 + lrow) * ldb + kcol;
    const bf16* gb1 = gb0 + (size_t)16 * ldb;
    bf16* la0 = &lA[wave * 1024];
    bf16* la1 = &lA[wave * 1024 + 512];
    bf16* lb0 = &lB[wave * 1024];
    bf16* lb1 = &lB[wave * 1024 + 512];

    const int wm    = (wave >> 1) * 64;
    const int wn    = (wave & 1) * 64;
    const int col16 = lane & 15;
    const int quad  = lane >> 4;
    const bf16* pa = &lA[(wm + col16) * 32 + quad * 8];
    const bf16* pb = &lB[(wn + col16) * 32 + quad * 8];

    for (int kb = 0; kb < K; kb += 32) {
        __builtin_amdgcn_global_load_lds(AS1C(ga0 + kb), AS3(la0), 16, 0, 0);
        __builtin_amdgcn_global_load_lds(AS1C(ga1 + kb), AS3(la1), 16, 0, 0);
        __builtin_amdgcn_global_load_lds(AS1C(gb0 + kb), AS3(lb0), 16, 0, 0);
        __builtin_amdgcn_global_load_lds(AS1C(gb1 + kb), AS3(lb1), 16, 0, 0);
        __syncthreads();

        bf16x8 av[4], bv[4];
        #pragma unroll
        for (int i = 0; i < 4; ++i) av[i] = *(const bf16x8*)(pa + i * 512);
        #pragma unroll
        for (int i = 0; i < 4; ++i) bv[i] = *(const bf16x8*)(pb + i * 512);

        #pragma unroll
        for (int mi = 0; mi < 4; ++mi)
            #pragma unroll
            for (int ni = 0; ni < 4; ++ni)
                acc[mi][ni] = MFMA16(av[mi], bv[ni], acc[mi][ni], 0, 0, 0);
        __syncthreads();
    }
}

// ---------------------------------------------------------------------------
// 256x256-tile deep-pipelined core (round-1 gemm_qkv loop, verbatim):
//   512 thr (8 waves: 2M x 4N), BK=32, 3-deep LDS ring (96 KB),
//   counted vmcnt(4) (never 0 in main loop), T2 XOR-swizzle, T5 setprio.
//   NT = K/32 (>= 2).  A: [256 x K] lda;  Bt: [256 x K] ldb.
// ---------------------------------------------------------------------------
__device__ __forceinline__ void gemm256(const bf16* __restrict__ Ablk,
                                        const bf16* __restrict__ Btblk,
                                        int lda, int ldb, int NT,
                                        f32x4 acc[8][4])
{
    __shared__ bf16 smem[49152];          // 96 KB = 3 bufs x (A 16KB + B 16KB)
    char* sm = (char*)smem;

    const int tid  = threadIdx.x;
    const int wave = tid >> 6;
    const int lane = tid & 63;
    const int col16 = lane & 15;
    const int quad  = lane >> 4;
    const int wm = (wave >> 2) * 128;     // 2 waves in M
    const int wn = (wave & 3) * 64;       // 4 waves in N

    // ---- staging: per-thread pre-swizzled global sources ----
    const int P0 = tid * 16;
    const int T0 = P0 ^ ((P0 >> 2) & 0x70) ^ ((P0 >> 4) & 0x10);
    const int r0 = T0 >> 6;               // 0..127
    const int ce = (T0 & 63) >> 1;        // element col offset, in {0,8,16,24}
    const bf16* gA0 = Ablk + (size_t)r0 * lda + ce;
    const bf16* gA1 = Ablk + (size_t)(r0 + 128) * lda + ce;
    const bf16* gB0 = Btblk + (size_t)r0 * ldb + ce;
    const bf16* gB1 = Btblk + (size_t)(r0 + 128) * ldb + ce;
    const int dA0 = wave * 1024;          // wave-uniform LDS dest bases
    const int dA1 = 8192  + wave * 1024;
    const int dB0 = 16384 + wave * 1024;
    const int dB1 = 24576 + wave * 1024;

    // ---- swizzled read offsets (constant across tiles) ----
    int offA[8], offB[4];
    #pragma unroll
    for (int mi = 0; mi < 8; ++mi) {
        int T = (wm + mi * 16 + col16) * 64 + quad * 16;
        offA[mi] = T ^ ((T >> 2) & 0x70);
    }
    #pragma unroll
    for (int ni = 0; ni < 4; ++ni) {
        int T = (wn + ni * 16 + col16) * 64 + quad * 16;
        offB[ni] = 16384 + (T ^ ((T >> 2) & 0x70));
    }

#define GLD(src, dst) __builtin_amdgcn_global_load_lds(AS1C(src), AS3(sm + (dst)), 16, 0, 0)

    // ---- prologue: stage tile 0 -> buf0, tile 1 -> buf1 ----
    GLD(gA0,      0 + dA0); GLD(gB0,      0 + dB0);
    GLD(gA1,      0 + dA1); GLD(gB1,      0 + dB1);
    GLD(gA0 + 32, 32768 + dA0); GLD(gB0 + 32, 32768 + dB0);
    GLD(gA1 + 32, 32768 + dA1); GLD(gB1 + 32, 32768 + dB1);
    asm volatile("s_waitcnt vmcnt(4)" ::: "memory");   // tile 0 landed
    __builtin_amdgcn_s_barrier();
    asm volatile("" ::: "memory");

    int buf = 0, sb = 2;
    for (int t = 0; t < NT; ++t) {
        const int  bb  = buf * 32768;
        const int  sbb = sb  * 32768;
        const int  kb  = (t + 2) * 32;
        const bool st  = (t + 2) < NT;

        // ================= phase A: mi 0-3 x ni 0-3 =================
        bf16x8 a0 = *(const bf16x8*)(sm + bb + offA[0]);
        bf16x8 a1 = *(const bf16x8*)(sm + bb + offA[1]);
        bf16x8 a2 = *(const bf16x8*)(sm + bb + offA[2]);
        bf16x8 a3 = *(const bf16x8*)(sm + bb + offA[3]);
        bf16x8 b0 = *(const bf16x8*)(sm + bb + offB[0]);
        bf16x8 b1 = *(const bf16x8*)(sm + bb + offB[1]);
        bf16x8 b2 = *(const bf16x8*)(sm + bb + offB[2]);
        bf16x8 b3 = *(const bf16x8*)(sm + bb + offB[3]);
        if (st) { GLD(gA0 + kb, sbb + dA0); GLD(gB0 + kb, sbb + dB0); }
        __builtin_amdgcn_s_setprio(1);
        acc[0][0] = MFMA16(a0, b0, acc[0][0], 0, 0, 0);
        acc[0][1] = MFMA16(a0, b1, acc[0][1], 0, 0, 0);
        acc[0][2] = MFMA16(a0, b2, acc[0][2], 0, 0, 0);
        acc[0][3] = MFMA16(a0, b3, acc[0][3], 0, 0, 0);
        acc[1][0] = MFMA16(a1, b0, acc[1][0], 0, 0, 0);
        acc[1][1] = MFMA16(a1, b1, acc[1][1], 0, 0, 0);
        acc[1][2] = MFMA16(a1, b2, acc[1][2], 0, 0, 0);
        acc[1][3] = MFMA16(a1, b3, acc[1][3], 0, 0, 0);
        acc[2][0] = MFMA16(a2, b0, acc[2][0], 0, 0, 0);
        acc[2][1] = MFMA16(a2, b1, acc[2][1], 0, 0, 0);
        acc[2][2] = MFMA16(a2, b2, acc[2][2], 0, 0, 0);
        acc[2][3] = MFMA16(a2, b3, acc[2][3], 0, 0, 0);
        acc[3][0] = MFMA16(a3, b0, acc[3][0], 0, 0, 0);
        acc[3][1] = MFMA16(a3, b1, acc[3][1], 0, 0, 0);
        acc[3][2] = MFMA16(a3, b2, acc[3][2], 0, 0, 0);
        acc[3][3] = MFMA16(a3, b3, acc[3][3], 0, 0, 0);
        __builtin_amdgcn_s_setprio(0);
        __builtin_amdgcn_s_barrier();
        asm volatile("" ::: "memory");

        // ================= phase B: mi 4-7 x ni 0-3 =================
        bf16x8 a4 = *(const bf16x8*)(sm + bb + offA[4]);
        bf16x8 a5 = *(const bf16x8*)(sm + bb + offA[5]);
        bf16x8 a6 = *(const bf16x8*)(sm + bb + offA[6]);
        bf16x8 a7 = *(const bf16x8*)(sm + bb + offA[7]);
        if (st) { GLD(gA1 + kb, sbb + dA1); GLD(gB1 + kb, sbb + dB1); }
        if (st) { asm volatile("s_waitcnt vmcnt(4)" ::: "memory"); }  // tile t+1 landed
        else    { asm volatile("s_waitcnt vmcnt(0)" ::: "memory"); }  // epilogue drain
        __builtin_amdgcn_s_setprio(1);
        acc[4][0] = MFMA16(a4, b0, acc[4][0], 0, 0, 0);
        acc[4][1] = MFMA16(a4, b1, acc[4][1], 0, 0, 0);
        acc[4][2] = MFMA16(a4, b2, acc[4][2], 0, 0, 0);
        acc[4][3] = MFMA16(a4, b3, acc[4][3], 0, 0, 0);
        acc[5][0] = MFMA16(a5, b0, acc[5][0], 0, 0, 0);
        acc[5][1] = MFMA16(a5, b1, acc[5][1], 0, 0, 0);
        acc[5][2] = MFMA16(a5, b2, acc[5][2], 0, 0, 0);
        acc[5][3] = MFMA16(a5, b3, acc[5][3], 0, 0, 0);
        acc[6][0] = MFMA16(a6, b0, acc[6][0], 0, 0, 0);
        acc[6][1] = MFMA16(a6, b1, acc[6][1], 0, 0, 0);
        acc[6][2] = MFMA16(a6, b2, acc[6][2], 0, 0, 0);
        acc[6][3] = MFMA16(a6, b3, acc[6][3], 0, 0, 0);
        acc[7][0] = MFMA16(a7, b0, acc[7][0], 0, 0, 0);
        acc[7][1] = MFMA16(a7, b1, acc[7][1], 0, 0, 0);
        acc[7][2] = MFMA16(a7, b2, acc[7][2], 0, 0, 0);
        acc[7][3] = MFMA16(a7, b3, acc[7][3], 0, 0, 0);
        __builtin_amdgcn_s_setprio(0);
        __builtin_amdgcn_s_barrier();
        asm volatile("" ::: "memory");

        buf = (buf == 2) ? 0 : buf + 1;
        sb  = (sb  == 2) ? 0 : sb  + 1;
    }
#undef GLD
}

// ---------------------------------------------------------------------------
// fp32 -> bf16 cast, 8 elems/thread
// ---------------------------------------------------------------------------
__global__ __launch_bounds__(256) void cast_bf16(const float* __restrict__ src,
                                                 u16* __restrict__ dst, int n8)
{
    int i = blockIdx.x * 256 + threadIdx.x;
    if (i >= n8) return;
    const float4* s = (const float4*)src + (size_t)i * 2;
    float4 f0 = s[0], f1 = s[1];
    u16x8 o;
    o[0] = f2bf(f0.x); o[1] = f2bf(f0.y); o[2] = f2bf(f0.z); o[3] = f2bf(f0.w);
    o[4] = f2bf(f1.x); o[5] = f2bf(f1.y); o[6] = f2bf(f1.z); o[7] = f2bf(f1.w);
    *((u16x8*)dst + i) = o;
}

// ---------------------------------------------------------------------------
// fused cast of all 3 weight matrices (dst regions contiguous: Wk|Wq|Wv)
// ---------------------------------------------------------------------------
__global__ __launch_bounds__(256) void cast_w(const float* __restrict__ Wk,
                                              const float* __restrict__ Wq,
                                              const float* __restrict__ Wv,
                                              u16* __restrict__ dst)
{
    const int bx = blockIdx.x;           // 0..6143
    const int region = bx >> 11;         // 0:k 1:q 2:v
    const int i = ((bx & 2047) << 8) + threadIdx.x;   // 0..524287
    const float* src = (region == 0) ? Wk : (region == 1) ? Wq : Wv;
    const float4* s = (const float4*)src + (size_t)i * 2;
    float4 f0 = s[0], f1 = s[1];
    u16x8 o;
    o[0] = f2bf(f0.x); o[1] = f2bf(f0.y); o[2] = f2bf(f0.z); o[3] = f2bf(f0.w);
    o[4] = f2bf(f1.x); o[5] = f2bf(f1.y); o[6] = f2bf(f1.z); o[7] = f2bf(f1.w);
    *((u16x8*)dst + (size_t)region * 524288 + i) = o;
}

// ---------------------------------------------------------------------------
// reduce 4 f32 partials + cast to bf16, 4 elems/thread
// ---------------------------------------------------------------------------
__global__ __launch_bounds__(256) void reduce_cast(const float* __restrict__ sp,
                                                   u16* __restrict__ dst, int n4)
{
    int i = blockIdx.x * 256 + threadIdx.x;
    if (i >= n4) return;
    float4 a = ((const float4*)sp)[i];
    float4 b = ((const float4*)(sp + 4194304))[i];
    float4 c = ((const float4*)(sp + 8388608))[i];
    float4 d = ((const float4*)(sp + 12582912))[i];
    u16x4 o;
    o[0] = f2bf((a.x + b.x) + (c.x + d.x));
    o[1] = f2bf((a.y + b.y) + (c.y + d.y));
    o[2] = f2bf((a.z + b.z) + (c.z + d.z));
    o[3] = f2bf((a.w + b.w) + (c.w + d.w));
    ((u16x4*)dst)[i] = o;
}

// ---------------------------------------------------------------------------
// GEMM1: fused QKV projection on the 256-core (round-1 structure, proven).
// q -> normal [16384][2048] bf16;  k,v -> transposed [bh][d][s] bf16.
// ---------------------------------------------------------------------------
__global__ __launch_bounds__(512, 2) void gemm_qkv(
    const bf16* __restrict__ xb,
    const bf16* __restrict__ Wkb, const bf16* __restrict__ Wqb, const bf16* __restrict__ Wvb,
    const float* __restrict__ bk, const float* __restrict__ bq, const float* __restrict__ bv,
    u16* __restrict__ qout, u16* __restrict__ kT, u16* __restrict__ vT)
{
    const int bx = blockIdx.x;            // m block 0..63 (256 rows each)
    const int by = blockIdx.y;            // n block 0..23
    const int region = by >> 3;           // 0:k 1:q 2:v
    const int nloc = (by & 7) << 8;       // n offset within region, 0..1792

    const bf16* W     = (region == 0) ? Wkb : (region == 1) ? Wqb : Wvb;
    const float* bias = (region == 0) ? bk  : (region == 1) ? bq  : bv;

    f32x4 acc[8][4] = {};
    gemm256(xb + (size_t)bx * 256 * 2048, W + (size_t)nloc * 2048,
            2048, 2048, 64, acc);

    const int lane = threadIdx.x & 63, wave = threadIdx.x >> 6;
    const int wm = (wave >> 2) * 128, wn = (wave & 3) * 64;
    const int col16 = lane & 15, quad = lane >> 4;

    if (region == 1) {
        // q: normal store, feature-contiguous
        #pragma unroll
        for (int mi = 0; mi < 8; ++mi) {
            int row = bx * 256 + wm + mi * 16 + quad * 4;
            #pragma unroll
            for (int ni = 0; ni < 4; ++ni) {
                int col = nloc + wn + ni * 16 + col16;
                float b = bias[col];
                #pragma unroll
                for (int r = 0; r < 4; ++r)
                    qout[(size_t)(row + r) * 2048 + col] = f2bf(acc[mi][ni][r] + b);
            }
        }
    } else {
        // k/v: transposed store [bh][d][s]; 4 consecutive s pack to 8B
        u16* T = (region == 0) ? kT : vT;
        const int b_ = bx >> 4;               // 64 m-blocks / 16 per batch
        const int h_ = nloc >> 9;
        const int bh = b_ * 4 + h_;
        #pragma unroll
        for (int mi = 0; mi < 8; ++mi) {
            int s = ((bx & 15) * 256) + wm + mi * 16 + quad * 4;   // within 4096
            #pragma unroll
            for (int ni = 0; ni < 4; ++ni) {
                int fcol = nloc + wn + ni * 16 + col16;  // feature in region
                int d = fcol & 511;
                float b = bias[fcol];
                u16x4 p;
                #pragma unroll
                for (int r = 0; r < 4; ++r) p[r] = f2bf(acc[mi][ni][r] + b);
                *(u16x4*)&T[((size_t)(bh * 512 + d)) * 4096 + s] = p;
            }
        }
    }
}

// ---------------------------------------------------------------------------
// GEMM2: split-K x4.  SP[kh][bh][e][d] (f32) = sum_{s in quarter} vT*kT.
// Grid (4,4,64): z = bh*4 + kh.  4 blocks/CU -> 16 waves/CU.
// ---------------------------------------------------------------------------
__global__ __launch_bounds__(256) void gemm_states(
    const u16* __restrict__ vT, const u16* __restrict__ kT, float* __restrict__ SP)
{
    const int z  = blockIdx.z;
    const int bh = z >> 2;
    const int kh = z & 3;
    const int m0 = blockIdx.x * 128;   // e
    const int n0 = blockIdx.y * 128;   // d

    f32x4 acc[4][4] = {};
    const size_t base = (size_t)bh * 2097152;
    const size_t koff = (size_t)kh * 1024;
    gemm_core((const bf16*)vT + base + (size_t)m0 * 4096 + koff,
              (const bf16*)kT + base + (size_t)n0 * 4096 + koff,
              4096, 4096, 1024, acc);

    float* P = SP + (size_t)kh * 4194304 + (size_t)bh * 262144;
    const int lane = threadIdx.x & 63, wave = threadIdx.x >> 6;
    const int wm = (wave >> 1) * 64, wn = (wave & 1) * 64;
    const int col16 = lane & 15, quad = lane >> 4;
    #pragma unroll
    for (int mi = 0; mi < 4; ++mi) {
        int row = m0 + wm + mi * 16 + quad * 4;
        #pragma unroll
        for (int ni = 0; ni < 4; ++ni) {
            int col = n0 + wn + ni * 16 + col16;
            #pragma unroll
            for (int r = 0; r < 4; ++r)
                P[(size_t)(row + r) * 512 + col] = acc[mi][ni][r];
        }
    }
}

// ---------------------------------------------------------------------------
// GEMM3 on the 256-core: out[bh][s][e] = sum_d q[b][s][h*512+d] * ST[bh][e][d].
// K=512 (NT=16).  Grid (16,2,16), 512 thr.
// ---------------------------------------------------------------------------
__global__ __launch_bounds__(512, 2) void gemm_out(
    const u16* __restrict__ qb, const u16* __restrict__ ST, float* __restrict__ out)
{
    const int bh = blockIdx.z;
    const int b_ = bh >> 2, h_ = bh & 3;
    const int m0 = blockIdx.x * 256;   // s
    const int n0 = blockIdx.y * 256;   // e

    f32x4 acc[8][4] = {};
    gemm256((const bf16*)qb + ((size_t)(b_ * 4096 + m0)) * 2048 + h_ * 512,
            (const bf16*)ST + (size_t)bh * 262144 + (size_t)n0 * 512,
            2048, 512, 16, acc);

    const int lane = threadIdx.x & 63, wave = threadIdx.x >> 6;
    const int wm = (wave >> 2) * 128, wn = (wave & 3) * 64;
    const int col16 = lane & 15, quad = lane >> 4;
    #pragma unroll
    for (int mi = 0; mi < 8; ++mi) {
        int row = m0 + wm + mi * 16 + quad * 4;
        #pragma unroll
        for (int ni = 0; ni < 4; ++ni) {
            int col = n0 + wn + ni * 16 + col16;
            #pragma unroll
            for (int r = 0; r < 4; ++r)
                out[(size_t)bh * 2097152 + (size_t)(row + r) * 512 + col] =
                    acc[mi][ni][r];
        }
    }
}

// ---------------------------------------------------------------------------
extern "C" void kernel_launch(void* const* d_in, const int* in_sizes, int n_in,
                              void* d_out, int out_size, void* d_ws, size_t ws_size,
                              hipStream_t stream)
{
    (void)in_sizes; (void)n_in; (void)out_size; (void)ws_size;
    const float* x  = (const float*)d_in[0];
    const float* Wk = (const float*)d_in[1];
    const float* bk = (const float*)d_in[2];
    const float* Wq = (const float*)d_in[3];
    const float* bq = (const float*)d_in[4];
    const float* Wv = (const float*)d_in[5];
    const float* bv = (const float*)d_in[6];
    float* out = (float*)d_out;

    // workspace layout (u16 elements), total 302 MB
    u16* ws  = (u16*)d_ws;
    u16* xb  = ws;                   // 16384*2048 (dead after gemm_qkv -> reused as SP)
    u16* Wkb = ws  + 33554432;       // 2048*2048 (k|q|v contiguous)
    u16* Wqb = Wkb + 4194304;
    u16* Wvb = Wqb + 4194304;
    u16* qb  = Wvb + 4194304;        // 16384*2048 (normal)
    u16* kT  = qb  + 33554432;       // [16][512][4096]
    u16* vT  = kT  + 33554432;       // [16][512][4096]
    u16* ST  = vT  + 33554432;       // [16][512][512]
    float* SP = (float*)xb;          // [4][16][512][512] f32 partials (67.1MB, exact fit)

    cast_bf16<<<16384, 256, 0, stream>>>(x, xb, 4194304);
    cast_w<<<6144, 256, 0, stream>>>(Wk, Wq, Wv, Wkb);

    gemm_qkv<<<dim3(64, 24), 512, 0, stream>>>(
        (const bf16*)xb, (const bf16*)Wkb, (const bf16*)Wqb, (const bf16*)Wvb,
        bk, bq, bv, qb, kT, vT);

    gemm_states<<<dim3(4, 4, 64), 256, 0, stream>>>(vT, kT, SP);
    reduce_cast<<<4096, 256, 0, stream>>>(SP, ST, 1048576);

    gemm_out<<<dim3(16, 2, 16), 512, 0, stream>>>(qb, ST, out);
}

// Round 5
// 785.795 us; speedup vs baseline: 1.0541x; 1.0105x over previous
//
#include <hip/hip_runtime.h>
#include <cstdint>
#include <cstddef>

typedef __bf16 bf16;
typedef bf16 bf16x8 __attribute__((ext_vector_type(8)));
typedef float f32x4 __attribute__((ext_vector_type(4)));
typedef unsigned short u16;
typedef u16 u16x4 __attribute__((ext_vector_type(4)));
typedef u16 u16x8 __attribute__((ext_vector_type(8)));

__device__ __forceinline__ u16 f2bf(float f) {
    uint32_t u = __builtin_bit_cast(uint32_t, f);
    u += 0x7FFFu + ((u >> 16) & 1u);
    return (u16)(u >> 16);
}

#define AS1C(p) ((const __attribute__((address_space(1))) uint32_t*)(p))
#define AS3(p)  ((__attribute__((address_space(3))) uint32_t*)(p))
#define MFMA16  __builtin_amdgcn_mfma_f32_16x16x32_bf16

// ---------------------------------------------------------------------------
// 128x128 m97-structure core — kept for gemm_states.
// ---------------------------------------------------------------------------
__device__ __forceinline__ void gemm_core(const bf16* __restrict__ Ablk,
                                          const bf16* __restrict__ Btblk,
                                          int lda, int ldb, int K,
                                          f32x4 acc[4][4])
{
    __shared__ bf16 lA[4096];
    __shared__ bf16 lB[4096];

    const int tid  = threadIdx.x;
    const int wave = tid >> 6;
    const int lane = tid & 63;
    const int lrow = lane >> 2;
    const int kcol = (lane & 3) << 3;

    const bf16* ga0 = Ablk  + (size_t)(wave * 32 + lrow) * lda + kcol;
    const bf16* ga1 = ga0 + (size_t)16 * lda;
    const bf16* gb0 = Btblk + (size_t)(wave * 32 + lrow) * ldb + kcol;
    const bf16* gb1 = gb0 + (size_t)16 * ldb;
    bf16* la0 = &lA[wave * 1024];
    bf16* la1 = &lA[wave * 1024 + 512];
    bf16* lb0 = &lB[wave * 1024];
    bf16* lb1 = &lB[wave * 1024 + 512];

    const int wm    = (wave >> 1) * 64;
    const int wn    = (wave & 1) * 64;
    const int col16 = lane & 15;
    const int quad  = lane >> 4;
    const bf16* pa = &lA[(wm + col16) * 32 + quad * 8];
    const bf16* pb = &lB[(wn + col16) * 32 + quad * 8];

    for (int kb = 0; kb < K; kb += 32) {
        __builtin_amdgcn_global_load_lds(AS1C(ga0 + kb), AS3(la0), 16, 0, 0);
        __builtin_amdgcn_global_load_lds(AS1C(ga1 + kb), AS3(la1), 16, 0, 0);
        __builtin_amdgcn_global_load_lds(AS1C(gb0 + kb), AS3(lb0), 16, 0, 0);
        __builtin_amdgcn_global_load_lds(AS1C(gb1 + kb), AS3(lb1), 16, 0, 0);
        __syncthreads();

        bf16x8 av[4], bv[4];
        #pragma unroll
        for (int i = 0; i < 4; ++i) av[i] = *(const bf16x8*)(pa + i * 512);
        #pragma unroll
        for (int i = 0; i < 4; ++i) bv[i] = *(const bf16x8*)(pb + i * 512);

        #pragma unroll
        for (int mi = 0; mi < 4; ++mi)
            #pragma unroll
            for (int ni = 0; ni < 4; ++ni)
                acc[mi][ni] = MFMA16(av[mi], bv[ni], acc[mi][ni], 0, 0, 0);
        __syncthreads();
    }
}

// ---------------------------------------------------------------------------
// 256x256-tile deep-pipelined core, single-phase-per-K-tile variant:
//   512 thr (8 waves: 2M x 4N), BK=32, 3-deep LDS ring (96 KB),
//   ONE barrier per K-tile, counted vmcnt(4) (0 only on the last tile),
//   GLD(t+2) issued post-barrier (provably race-free: reads(t-1) are
//   use-drained + lgkmcnt(0) before barrier(t)), T2 XOR-swizzle, T5 setprio.
//   B-fragments read first so the first MFMA row unblocks after 5 reads.
// ---------------------------------------------------------------------------
__device__ __forceinline__ void gemm256(const bf16* __restrict__ Ablk,
                                        const bf16* __restrict__ Btblk,
                                        int lda, int ldb, int NT,
                                        f32x4 acc[8][4])
{
    __shared__ bf16 smem[49152];          // 96 KB = 3 bufs x (A 16KB + B 16KB)
    char* sm = (char*)smem;

    const int tid  = threadIdx.x;
    const int wave = tid >> 6;
    const int lane = tid & 63;
    const int col16 = lane & 15;
    const int quad  = lane >> 4;
    const int wm = (wave >> 2) * 128;     // 2 waves in M
    const int wn = (wave & 3) * 64;       // 4 waves in N

    // ---- staging: per-thread pre-swizzled global sources ----
    const int P0 = tid * 16;
    const int T0 = P0 ^ ((P0 >> 2) & 0x70) ^ ((P0 >> 4) & 0x10);
    const int r0 = T0 >> 6;               // 0..127
    const int ce = (T0 & 63) >> 1;        // element col offset, in {0,8,16,24}
    const bf16* gA0 = Ablk + (size_t)r0 * lda + ce;
    const bf16* gA1 = Ablk + (size_t)(r0 + 128) * lda + ce;
    const bf16* gB0 = Btblk + (size_t)r0 * ldb + ce;
    const bf16* gB1 = Btblk + (size_t)(r0 + 128) * ldb + ce;
    const int dA0 = wave * 1024;          // wave-uniform LDS dest bases
    const int dA1 = 8192  + wave * 1024;
    const int dB0 = 16384 + wave * 1024;
    const int dB1 = 24576 + wave * 1024;

    // ---- swizzled read offsets (constant across tiles) ----
    int offA[8], offB[4];
    #pragma unroll
    for (int mi = 0; mi < 8; ++mi) {
        int T = (wm + mi * 16 + col16) * 64 + quad * 16;
        offA[mi] = T ^ ((T >> 2) & 0x70);
    }
    #pragma unroll
    for (int ni = 0; ni < 4; ++ni) {
        int T = (wn + ni * 16 + col16) * 64 + quad * 16;
        offB[ni] = 16384 + (T ^ ((T >> 2) & 0x70));
    }

#define GLD(src, dst) __builtin_amdgcn_global_load_lds(AS1C(src), AS3(sm + (dst)), 16, 0, 0)

    // ---- prologue: stage tile 0 -> buf0, tile 1 -> buf1 (8 loads) ----
    GLD(gA0,      0 + dA0); GLD(gB0,      0 + dB0);
    GLD(gA1,      0 + dA1); GLD(gB1,      0 + dB1);
    GLD(gA0 + 32, 32768 + dA0); GLD(gB0 + 32, 32768 + dB0);
    GLD(gA1 + 32, 32768 + dA1); GLD(gB1 + 32, 32768 + dB1);

    int bb = 0;   // byte base of buf holding tile t: rotates 0,32768,65536
    for (int t = 0; t < NT; ++t) {
        // ensure tile t landed (outstanding: {t, t+1} = 8 loads normally)
        if (t + 1 < NT) { asm volatile("s_waitcnt vmcnt(4)" ::: "memory"); }
        else            { asm volatile("s_waitcnt vmcnt(0)" ::: "memory"); }
        asm volatile("s_waitcnt lgkmcnt(0)" ::: "memory");   // reads(t-1) drained
        __builtin_amdgcn_s_barrier();
        asm volatile("" ::: "memory");

        // stage tile t+2 into buf[(t+2)%3] (overwrites buf of t-1; safe)
        const int bb2 = (bb + 65536 >= 98304) ? bb - 32768 : bb + 65536;
        if (t + 2 < NT) {
            const int kb = (t + 2) * 32;
            GLD(gA0 + kb, bb2 + dA0); GLD(gA1 + kb, bb2 + dA1);
            GLD(gB0 + kb, bb2 + dB0); GLD(gB1 + kb, bb2 + dB1);
        }

        // read tile t fragments: B first, then A (first MFMA row needs b0-3,a0)
        bf16x8 b0 = *(const bf16x8*)(sm + bb + offB[0]);
        bf16x8 b1 = *(const bf16x8*)(sm + bb + offB[1]);
        bf16x8 b2 = *(const bf16x8*)(sm + bb + offB[2]);
        bf16x8 b3 = *(const bf16x8*)(sm + bb + offB[3]);
        bf16x8 a0 = *(const bf16x8*)(sm + bb + offA[0]);
        bf16x8 a1 = *(const bf16x8*)(sm + bb + offA[1]);
        bf16x8 a2 = *(const bf16x8*)(sm + bb + offA[2]);
        bf16x8 a3 = *(const bf16x8*)(sm + bb + offA[3]);
        bf16x8 a4 = *(const bf16x8*)(sm + bb + offA[4]);
        bf16x8 a5 = *(const bf16x8*)(sm + bb + offA[5]);
        bf16x8 a6 = *(const bf16x8*)(sm + bb + offA[6]);
        bf16x8 a7 = *(const bf16x8*)(sm + bb + offA[7]);

        __builtin_amdgcn_s_setprio(1);
        acc[0][0] = MFMA16(a0, b0, acc[0][0], 0, 0, 0);
        acc[0][1] = MFMA16(a0, b1, acc[0][1], 0, 0, 0);
        acc[0][2] = MFMA16(a0, b2, acc[0][2], 0, 0, 0);
        acc[0][3] = MFMA16(a0, b3, acc[0][3], 0, 0, 0);
        acc[1][0] = MFMA16(a1, b0, acc[1][0], 0, 0, 0);
        acc[1][1] = MFMA16(a1, b1, acc[1][1], 0, 0, 0);
        acc[1][2] = MFMA16(a1, b2, acc[1][2], 0, 0, 0);
        acc[1][3] = MFMA16(a1, b3, acc[1][3], 0, 0, 0);
        acc[2][0] = MFMA16(a2, b0, acc[2][0], 0, 0, 0);
        acc[2][1] = MFMA16(a2, b1, acc[2][1], 0, 0, 0);
        acc[2][2] = MFMA16(a2, b2, acc[2][2], 0, 0, 0);
        acc[2][3] = MFMA16(a2, b3, acc[2][3], 0, 0, 0);
        acc[3][0] = MFMA16(a3, b0, acc[3][0], 0, 0, 0);
        acc[3][1] = MFMA16(a3, b1, acc[3][1], 0, 0, 0);
        acc[3][2] = MFMA16(a3, b2, acc[3][2], 0, 0, 0);
        acc[3][3] = MFMA16(a3, b3, acc[3][3], 0, 0, 0);
        acc[4][0] = MFMA16(a4, b0, acc[4][0], 0, 0, 0);
        acc[4][1] = MFMA16(a4, b1, acc[4][1], 0, 0, 0);
        acc[4][2] = MFMA16(a4, b2, acc[4][2], 0, 0, 0);
        acc[4][3] = MFMA16(a4, b3, acc[4][3], 0, 0, 0);
        acc[5][0] = MFMA16(a5, b0, acc[5][0], 0, 0, 0);
        acc[5][1] = MFMA16(a5, b1, acc[5][1], 0, 0, 0);
        acc[5][2] = MFMA16(a5, b2, acc[5][2], 0, 0, 0);
        acc[5][3] = MFMA16(a5, b3, acc[5][3], 0, 0, 0);
        acc[6][0] = MFMA16(a6, b0, acc[6][0], 0, 0, 0);
        acc[6][1] = MFMA16(a6, b1, acc[6][1], 0, 0, 0);
        acc[6][2] = MFMA16(a6, b2, acc[6][2], 0, 0, 0);
        acc[6][3] = MFMA16(a6, b3, acc[6][3], 0, 0, 0);
        acc[7][0] = MFMA16(a7, b0, acc[7][0], 0, 0, 0);
        acc[7][1] = MFMA16(a7, b1, acc[7][1], 0, 0, 0);
        acc[7][2] = MFMA16(a7, b2, acc[7][2], 0, 0, 0);
        acc[7][3] = MFMA16(a7, b3, acc[7][3], 0, 0, 0);
        __builtin_amdgcn_s_setprio(0);

        bb = (bb >= 65536) ? 0 : bb + 32768;
    }
#undef GLD
}

// ---------------------------------------------------------------------------
// fp32 -> bf16 cast, 8 elems/thread
// ---------------------------------------------------------------------------
__global__ __launch_bounds__(256) void cast_bf16(const float* __restrict__ src,
                                                 u16* __restrict__ dst, int n8)
{
    int i = blockIdx.x * 256 + threadIdx.x;
    if (i >= n8) return;
    const float4* s = (const float4*)src + (size_t)i * 2;
    float4 f0 = s[0], f1 = s[1];
    u16x8 o;
    o[0] = f2bf(f0.x); o[1] = f2bf(f0.y); o[2] = f2bf(f0.z); o[3] = f2bf(f0.w);
    o[4] = f2bf(f1.x); o[5] = f2bf(f1.y); o[6] = f2bf(f1.z); o[7] = f2bf(f1.w);
    *((u16x8*)dst + i) = o;
}

// ---------------------------------------------------------------------------
// fused cast of all 3 weight matrices (dst regions contiguous: Wk|Wq|Wv)
// ---------------------------------------------------------------------------
__global__ __launch_bounds__(256) void cast_w(const float* __restrict__ Wk,
                                              const float* __restrict__ Wq,
                                              const float* __restrict__ Wv,
                                              u16* __restrict__ dst)
{
    const int bx = blockIdx.x;           // 0..6143
    const int region = bx >> 11;         // 0:k 1:q 2:v
    const int i = ((bx & 2047) << 8) + threadIdx.x;   // 0..524287
    const float* src = (region == 0) ? Wk : (region == 1) ? Wq : Wv;
    const float4* s = (const float4*)src + (size_t)i * 2;
    float4 f0 = s[0], f1 = s[1];
    u16x8 o;
    o[0] = f2bf(f0.x); o[1] = f2bf(f0.y); o[2] = f2bf(f0.z); o[3] = f2bf(f0.w);
    o[4] = f2bf(f1.x); o[5] = f2bf(f1.y); o[6] = f2bf(f1.z); o[7] = f2bf(f1.w);
    *((u16x8*)dst + (size_t)region * 524288 + i) = o;
}

// ---------------------------------------------------------------------------
// reduce 4 f32 partials + cast to bf16, 4 elems/thread
// ---------------------------------------------------------------------------
__global__ __launch_bounds__(256) void reduce_cast(const float* __restrict__ sp,
                                                   u16* __restrict__ dst, int n4)
{
    int i = blockIdx.x * 256 + threadIdx.x;
    if (i >= n4) return;
    float4 a = ((const float4*)sp)[i];
    float4 b = ((const float4*)(sp + 4194304))[i];
    float4 c = ((const float4*)(sp + 8388608))[i];
    float4 d = ((const float4*)(sp + 12582912))[i];
    u16x4 o;
    o[0] = f2bf((a.x + b.x) + (c.x + d.x));
    o[1] = f2bf((a.y + b.y) + (c.y + d.y));
    o[2] = f2bf((a.z + b.z) + (c.z + d.z));
    o[3] = f2bf((a.w + b.w) + (c.w + d.w));
    ((u16x4*)dst)[i] = o;
}

// ---------------------------------------------------------------------------
// GEMM1: fused QKV projection on the 256-core.
// q -> normal [16384][2048] bf16;  k,v -> transposed [bh][d][s] bf16.
// ---------------------------------------------------------------------------
__global__ __launch_bounds__(512, 2) void gemm_qkv(
    const bf16* __restrict__ xb,
    const bf16* __restrict__ Wkb, const bf16* __restrict__ Wqb, const bf16* __restrict__ Wvb,
    const float* __restrict__ bk, const float* __restrict__ bq, const float* __restrict__ bv,
    u16* __restrict__ qout, u16* __restrict__ kT, u16* __restrict__ vT)
{
    const int bx = blockIdx.x;            // m block 0..63 (256 rows each)
    const int by = blockIdx.y;            // n block 0..23
    const int region = by >> 3;           // 0:k 1:q 2:v
    const int nloc = (by & 7) << 8;       // n offset within region, 0..1792

    const bf16* W     = (region == 0) ? Wkb : (region == 1) ? Wqb : Wvb;
    const float* bias = (region == 0) ? bk  : (region == 1) ? bq  : bv;

    f32x4 acc[8][4] = {};
    gemm256(xb + (size_t)bx * 256 * 2048, W + (size_t)nloc * 2048,
            2048, 2048, 64, acc);

    const int lane = threadIdx.x & 63, wave = threadIdx.x >> 6;
    const int wm = (wave >> 2) * 128, wn = (wave & 3) * 64;
    const int col16 = lane & 15, quad = lane >> 4;

    if (region == 1) {
        // q: normal store, feature-contiguous
        #pragma unroll
        for (int mi = 0; mi < 8; ++mi) {
            int row = bx * 256 + wm + mi * 16 + quad * 4;
            #pragma unroll
            for (int ni = 0; ni < 4; ++ni) {
                int col = nloc + wn + ni * 16 + col16;
                float b = bias[col];
                #pragma unroll
                for (int r = 0; r < 4; ++r)
                    qout[(size_t)(row + r) * 2048 + col] = f2bf(acc[mi][ni][r] + b);
            }
        }
    } else {
        // k/v: transposed store [bh][d][s]; 4 consecutive s pack to 8B
        u16* T = (region == 0) ? kT : vT;
        const int b_ = bx >> 4;               // 64 m-blocks / 16 per batch
        const int h_ = nloc >> 9;
        const int bh = b_ * 4 + h_;
        #pragma unroll
        for (int mi = 0; mi < 8; ++mi) {
            int s = ((bx & 15) * 256) + wm + mi * 16 + quad * 4;   // within 4096
            #pragma unroll
            for (int ni = 0; ni < 4; ++ni) {
                int fcol = nloc + wn + ni * 16 + col16;  // feature in region
                int d = fcol & 511;
                float b = bias[fcol];
                u16x4 p;
                #pragma unroll
                for (int r = 0; r < 4; ++r) p[r] = f2bf(acc[mi][ni][r] + b);
                *(u16x4*)&T[((size_t)(bh * 512 + d)) * 4096 + s] = p;
            }
        }
    }
}

// ---------------------------------------------------------------------------
// GEMM2: split-K x4.  SP[kh][bh][e][d] (f32) = sum_{s in quarter} vT*kT.
// Grid (4,4,64): 4 blocks/CU -> 16 waves/CU.
// ---------------------------------------------------------------------------
__global__ __launch_bounds__(256) void gemm_states(
    const u16* __restrict__ vT, const u16* __restrict__ kT, float* __restrict__ SP)
{
    const int z  = blockIdx.z;
    const int bh = z >> 2;
    const int kh = z & 3;
    const int m0 = blockIdx.x * 128;   // e
    const int n0 = blockIdx.y * 128;   // d

    f32x4 acc[4][4] = {};
    const size_t base = (size_t)bh * 2097152;
    const size_t koff = (size_t)kh * 1024;
    gemm_core((const bf16*)vT + base + (size_t)m0 * 4096 + koff,
              (const bf16*)kT + base + (size_t)n0 * 4096 + koff,
              4096, 4096, 1024, acc);

    float* P = SP + (size_t)kh * 4194304 + (size_t)bh * 262144;
    const int lane = threadIdx.x & 63, wave = threadIdx.x >> 6;
    const int wm = (wave >> 1) * 64, wn = (wave & 1) * 64;
    const int col16 = lane & 15, quad = lane >> 4;
    #pragma unroll
    for (int mi = 0; mi < 4; ++mi) {
        int row = m0 + wm + mi * 16 + quad * 4;
        #pragma unroll
        for (int ni = 0; ni < 4; ++ni) {
            int col = n0 + wn + ni * 16 + col16;
            #pragma unroll
            for (int r = 0; r < 4; ++r)
                P[(size_t)(row + r) * 512 + col] = acc[mi][ni][r];
        }
    }
}

// ---------------------------------------------------------------------------
// GEMM3 on the 256-core: out[bh][s][e] = sum_d q[b][s][h*512+d] * ST[bh][e][d].
// K=512 (NT=16).  Grid (16,2,16), 512 thr.
// ---------------------------------------------------------------------------
__global__ __launch_bounds__(512, 2) void gemm_out(
    const u16* __restrict__ qb, const u16* __restrict__ ST, float* __restrict__ out)
{
    const int bh = blockIdx.z;
    const int b_ = bh >> 2, h_ = bh & 3;
    const int m0 = blockIdx.x * 256;   // s
    const int n0 = blockIdx.y * 256;   // e

    f32x4 acc[8][4] = {};
    gemm256((const bf16*)qb + ((size_t)(b_ * 4096 + m0)) * 2048 + h_ * 512,
            (const bf16*)ST + (size_t)bh * 262144 + (size_t)n0 * 512,
            2048, 512, 16, acc);

    const int lane = threadIdx.x & 63, wave = threadIdx.x >> 6;
    const int wm = (wave >> 2) * 128, wn = (wave & 3) * 64;
    const int col16 = lane & 15, quad = lane >> 4;
    #pragma unroll
    for (int mi = 0; mi < 8; ++mi) {
        int row = m0 + wm + mi * 16 + quad * 4;
        #pragma unroll
        for (int ni = 0; ni < 4; ++ni) {
            int col = n0 + wn + ni * 16 + col16;
            #pragma unroll
            for (int r = 0; r < 4; ++r)
                out[(size_t)bh * 2097152 + (size_t)(row + r) * 512 + col] =
                    acc[mi][ni][r];
        }
    }
}

// ---------------------------------------------------------------------------
extern "C" void kernel_launch(void* const* d_in, const int* in_sizes, int n_in,
                              void* d_out, int out_size, void* d_ws, size_t ws_size,
                              hipStream_t stream)
{
    (void)in_sizes; (void)n_in; (void)out_size; (void)ws_size;
    const float* x  = (const float*)d_in[0];
    const float* Wk = (const float*)d_in[1];
    const float* bk = (const float*)d_in[2];
    const float* Wq = (const float*)d_in[3];
    const float* bq = (const float*)d_in[4];
    const float* Wv = (const float*)d_in[5];
    const float* bv = (const float*)d_in[6];
    float* out = (float*)d_out;

    // workspace layout (u16 elements), total 302 MB
    u16* ws  = (u16*)d_ws;
    u16* xb  = ws;                   // 16384*2048 (dead after gemm_qkv -> reused as SP)
    u16* Wkb = ws  + 33554432;       // 2048*2048 (k|q|v contiguous)
    u16* Wqb = Wkb + 4194304;
    u16* Wvb = Wqb + 4194304;
    u16* qb  = Wvb + 4194304;        // 16384*2048 (normal)
    u16* kT  = qb  + 33554432;       // [16][512][4096]
    u16* vT  = kT  + 33554432;       // [16][512][4096]
    u16* ST  = vT  + 33554432;       // [16][512][512]
    float* SP = (float*)xb;          // [4][16][512][512] f32 partials (67.1MB, exact fit)

    cast_bf16<<<16384, 256, 0, stream>>>(x, xb, 4194304);
    cast_w<<<6144, 256, 0, stream>>>(Wk, Wq, Wv, Wkb);

    gemm_qkv<<<dim3(64, 24), 512, 0, stream>>>(
        (const bf16*)xb, (const bf16*)Wkb, (const bf16*)Wqb, (const bf16*)Wvb,
        bk, bq, bv, qb, kT, vT);

    gemm_states<<<dim3(4, 4, 64), 256, 0, stream>>>(vT, kT, SP);
    reduce_cast<<<4096, 256, 0, stream>>>(SP, ST, 1048576);

    gemm_out<<<dim3(16, 2, 16), 512, 0, stream>>>(qb, ST, out);
}